// Round 1
// baseline (596.136 us; speedup 1.0000x reference)
//
#include <hip/hip_runtime.h>
#include <hip/hip_bf16.h>

// ---------------- degree count ----------------
__global__ __launch_bounds__(256) void count_deg(const int* __restrict__ dst,
                                                 int* __restrict__ deg, int E) {
    int i = blockIdx.x * blockDim.x + threadIdx.x;
    if (i < E) atomicAdd(&deg[dst[i]], 1);
}

__global__ __launch_bounds__(256) void dinv_kernel(const int* __restrict__ deg,
                                                   float* __restrict__ dinv, int N) {
    int i = blockIdx.x * blockDim.x + threadIdx.x;
    if (i < N) dinv[i] = rsqrtf((float)deg[i] + 1.0f);
}

// ---------------- exclusive scan (3 kernels) ----------------
#define SCAN_BLK 1024

__global__ __launch_bounds__(256) void scan1(const int* __restrict__ deg,
                                             int* __restrict__ rp,
                                             int* __restrict__ bsum, int N) {
    __shared__ int sdata[256];
    int t = threadIdx.x;
    int base = blockIdx.x * SCAN_BLK + t * 4;
    int v[4];
    int s = 0;
#pragma unroll
    for (int j = 0; j < 4; ++j) {
        int idx = base + j;
        v[j] = (idx < N) ? deg[idx] : 0;
        s += v[j];
    }
    sdata[t] = s;
    __syncthreads();
    for (int off = 1; off < 256; off <<= 1) {
        int y = (t >= off) ? sdata[t - off] : 0;
        __syncthreads();
        sdata[t] += y;
        __syncthreads();
    }
    int incl = sdata[t];
    int run = incl - s;  // exclusive prefix for this thread within block
#pragma unroll
    for (int j = 0; j < 4; ++j) {
        int idx = base + j;
        if (idx < N) rp[idx] = run;
        run += v[j];
    }
    if (t == 255) bsum[blockIdx.x] = incl;
}

__global__ __launch_bounds__(1024) void scan2(int* __restrict__ bsum, int NB) {
    __shared__ int sd[1024];
    int t = threadIdx.x;
    int v = (t < NB) ? bsum[t] : 0;
    sd[t] = v;
    __syncthreads();
    for (int off = 1; off < 1024; off <<= 1) {
        int y = (t >= off) ? sd[t - off] : 0;
        __syncthreads();
        sd[t] += y;
        __syncthreads();
    }
    if (t < NB) bsum[t] = sd[t] - v;  // exclusive
}

__global__ __launch_bounds__(256) void scan3(int* __restrict__ rp,
                                             const int* __restrict__ bsum,
                                             int N, int E) {
    int i = blockIdx.x * blockDim.x + threadIdx.x;
    if (i < N) rp[i] += bsum[i / SCAN_BLK];
    if (i == 0) rp[N] = E;
}

// ---------------- CSR fill ----------------
__global__ __launch_bounds__(256) void fill_csr(const int* __restrict__ src,
                                                const int* __restrict__ dst,
                                                const int* __restrict__ rp,
                                                int* __restrict__ fill,
                                                int* __restrict__ col, int E) {
    int i = blockIdx.x * blockDim.x + threadIdx.x;
    if (i < E) {
        int d = dst[i];
        int p = atomicAdd(&fill[d], 1);
        col[rp[d] + p] = src[i];
    }
}

// ---------------- GEMM: out[N][64] = A[N][64] @ W[64][64] ----------------
__global__ __launch_bounds__(256) void gemm64(const float* __restrict__ A,
                                              const float* __restrict__ W,
                                              float* __restrict__ out, int N) {
    __shared__ float sW[64][64];
    __shared__ float sX[64][65];  // +1 pad to break bank conflicts
    int t = threadIdx.x;
    for (int i = t; i < 4096; i += 256) sW[i >> 6][i & 63] = W[i];
    int row0 = blockIdx.x * 64;
    for (int i = t; i < 4096; i += 256) {
        int r = i >> 6, c = i & 63;
        int gr = row0 + r;
        sX[r][c] = (gr < N) ? A[(size_t)gr * 64 + c] : 0.f;
    }
    __syncthreads();
    int r = t >> 2;             // 0..63
    int c0 = (t & 3) * 16;      // 0,16,32,48
    float acc[16];
#pragma unroll
    for (int j = 0; j < 16; ++j) acc[j] = 0.f;
#pragma unroll
    for (int k = 0; k < 64; ++k) {
        float xv = sX[r][k];
#pragma unroll
        for (int j = 0; j < 16; ++j) acc[j] += xv * sW[k][c0 + j];
    }
    int gr = row0 + r;
    if (gr < N) {
#pragma unroll
        for (int j = 0; j < 16; ++j) out[(size_t)gr * 64 + c0 + j] = acc[j];
    }
}

// ---------------- GCN aggregation (wave per dst row, lane = channel) -------
template <bool NV>
__global__ __launch_bounds__(256) void agg_kernel(const float* __restrict__ xw,
                                                  const int* __restrict__ rp,
                                                  const int* __restrict__ col,
                                                  const float* __restrict__ dinv,
                                                  const float* __restrict__ bias,
                                                  const float* __restrict__ wfc,
                                                  float* __restrict__ out, int N) {
    int wid = blockIdx.x * 4 + (threadIdx.x >> 6);
    int lane = threadIdx.x & 63;
    if (wid >= N) return;
    float di = dinv[wid];
    float acc = xw[(size_t)wid * 64 + lane] * (di * di);
    int e0 = rp[wid], e1 = rp[wid + 1];
    for (int e = e0; e < e1; ++e) {
        int s = col[e];
        acc += xw[(size_t)s * 64 + lane] * (dinv[s] * di);
    }
    float v = acc + bias[lane];
    v = v > 0.f ? v : 0.f;
    if (NV) {
        float p = v * wfc[lane];
#pragma unroll
        for (int off = 32; off; off >>= 1) p += __shfl_down(p, off);
        if (lane == 0) out[wid] = p;
    } else {
        out[(size_t)wid * 64 + lane] = v;
    }
}

// ---------------- fused edge-pred + route sum (wave per route) ----------------
__global__ __launch_bounds__(256) void route_kernel(const float* __restrict__ nv,
                                                    const int* __restrict__ src,
                                                    const float* __restrict__ ea,
                                                    const float* __restrict__ wfc,
                                                    const float* __restrict__ bfc,
                                                    const int* __restrict__ routes,
                                                    float* __restrict__ out, int R) {
    int r = blockIdx.x * 4 + (threadIdx.x >> 6);
    int lane = threadIdx.x & 63;
    if (r >= R) return;
    int s0 = routes[2 * r], s1 = routes[2 * r + 1];
    float w0 = wfc[64], w1 = wfc[65], b = bfc[0];
    float acc = 0.f;
    for (int e = s0 + lane; e < s1; e += 64) {
        float2 a = *(const float2*)(&ea[2 * (size_t)e]);
        acc += nv[src[e]] + a.x * w0 + a.y * w1 + b;
    }
#pragma unroll
    for (int off = 32; off; off >>= 1) acc += __shfl_down(acc, off);
    if (lane == 0) out[r] = acc;
}

extern "C" void kernel_launch(void* const* d_in, const int* in_sizes, int n_in,
                              void* d_out, int out_size, void* d_ws, size_t ws_size,
                              hipStream_t stream) {
    const float* x   = (const float*)d_in[0];
    const float* ea  = (const float*)d_in[1];
    const float* W1  = (const float*)d_in[2];
    const float* b1  = (const float*)d_in[3];
    const float* W2  = (const float*)d_in[4];
    const float* b2  = (const float*)d_in[5];
    const float* Wfc = (const float*)d_in[6];
    const float* bfc = (const float*)d_in[7];
    const int* eidx  = (const int*)d_in[8];
    const int* routes= (const int*)d_in[9];

    int N = in_sizes[0] / 64;
    int E = in_sizes[8] / 2;
    int R = in_sizes[9] / 2;
    const int* src = eidx;
    const int* dst = eidx + E;

    char* ws = (char*)d_ws;
    size_t off = 0;
    auto alloc = [&](size_t bytes) -> void* {
        off = (off + 255) & ~(size_t)255;
        void* p = ws + off;
        off += bytes;
        return p;
    };

    float* dinv = (float*)alloc((size_t)N * 4);
    int*   deg  = (int*)alloc((size_t)N * 4);
    int*   rp   = (int*)alloc((size_t)(N + 1) * 4);
    int*   fill = (int*)alloc((size_t)N * 4);
    int*   col  = (int*)alloc((size_t)E * 4);
    float* bufA = (float*)alloc((size_t)N * 64 * 4);
    float* bufB = (float*)alloc((size_t)N * 64 * 4);
    float* nv   = (float*)alloc((size_t)N * 4);
    int*   bsum = (int*)alloc(4096);

    hipMemsetAsync(deg, 0, (size_t)N * 4, stream);
    hipMemsetAsync(fill, 0, (size_t)N * 4, stream);

    int eb = (E + 255) / 256;
    int nb = (N + 255) / 256;
    int nb1024 = (N + SCAN_BLK - 1) / SCAN_BLK;

    count_deg<<<eb, 256, 0, stream>>>(dst, deg, E);
    dinv_kernel<<<nb, 256, 0, stream>>>(deg, dinv, N);
    scan1<<<nb1024, 256, 0, stream>>>(deg, rp, bsum, N);
    scan2<<<1, 1024, 0, stream>>>(bsum, nb1024);
    scan3<<<nb, 256, 0, stream>>>(rp, bsum, N, E);
    fill_csr<<<eb, 256, 0, stream>>>(src, dst, rp, fill, col, E);

    // layer 1
    gemm64<<<(N + 63) / 64, 256, 0, stream>>>(x, W1, bufA, N);
    agg_kernel<false><<<(N + 3) / 4, 256, 0, stream>>>(bufA, rp, col, dinv, b1, nullptr, bufB, N);
    // layer 2 (fuses Wfc[:64] dot -> nv)
    gemm64<<<(N + 63) / 64, 256, 0, stream>>>(bufB, W2, bufA, N);
    agg_kernel<true><<<(N + 3) / 4, 256, 0, stream>>>(bufA, rp, col, dinv, b2, Wfc, nv, N);

    route_kernel<<<(R + 3) / 4, 256, 0, stream>>>(nv, src, ea, Wfc, bfc, routes, (float*)d_out, R);
}

// Round 2
// 468.548 us; speedup vs baseline: 1.2723x; 1.2723x over previous
//
#include <hip/hip_runtime.h>
#include <hip/hip_bf16.h>

__device__ __forceinline__ unsigned short f2bf(float f) {
    unsigned int u = __float_as_uint(f);
    unsigned int r = (u + 0x7FFFu + ((u >> 16) & 1u)) >> 16;
    return (unsigned short)r;
}
__device__ __forceinline__ float bf2f(unsigned short b) {
    return __uint_as_float(((unsigned int)b) << 16);
}

// ---------------- degree count ----------------
__global__ __launch_bounds__(256) void count_deg(const int* __restrict__ dst,
                                                 int* __restrict__ deg, int E) {
    int i = blockIdx.x * blockDim.x + threadIdx.x;
    if (i < E) atomicAdd(&deg[dst[i]], 1);
}

// ---------------- exclusive scan (3 kernels); scan1 also writes dinv ----------
#define SCAN_BLK 1024

__global__ __launch_bounds__(256) void scan1(const int* __restrict__ deg,
                                             int* __restrict__ rp,
                                             float* __restrict__ dinv,
                                             int* __restrict__ bsum, int N) {
    __shared__ int sdata[256];
    int t = threadIdx.x;
    int base = blockIdx.x * SCAN_BLK + t * 4;
    int v[4];
    int s = 0;
#pragma unroll
    for (int j = 0; j < 4; ++j) {
        int idx = base + j;
        v[j] = (idx < N) ? deg[idx] : 0;
        if (idx < N) dinv[idx] = rsqrtf((float)v[j] + 1.0f);
        s += v[j];
    }
    sdata[t] = s;
    __syncthreads();
    for (int off = 1; off < 256; off <<= 1) {
        int y = (t >= off) ? sdata[t - off] : 0;
        __syncthreads();
        sdata[t] += y;
        __syncthreads();
    }
    int incl = sdata[t];
    int run = incl - s;
#pragma unroll
    for (int j = 0; j < 4; ++j) {
        int idx = base + j;
        if (idx < N) rp[idx] = run;
        run += v[j];
    }
    if (t == 255) bsum[blockIdx.x] = incl;
}

__global__ __launch_bounds__(1024) void scan2(int* __restrict__ bsum, int NB) {
    __shared__ int sd[1024];
    int t = threadIdx.x;
    int v = (t < NB) ? bsum[t] : 0;
    sd[t] = v;
    __syncthreads();
    for (int off = 1; off < 1024; off <<= 1) {
        int y = (t >= off) ? sd[t - off] : 0;
        __syncthreads();
        sd[t] += y;
        __syncthreads();
    }
    if (t < NB) bsum[t] = sd[t] - v;
}

__global__ __launch_bounds__(256) void scan3(int* __restrict__ rp,
                                             const int* __restrict__ bsum,
                                             int N, int E) {
    int i = blockIdx.x * blockDim.x + threadIdx.x;
    if (i < N) rp[i] += bsum[i / SCAN_BLK];
    if (i == 0) rp[N] = E;
}

// ---------------- CSR fill ----------------
__global__ __launch_bounds__(256) void fill_csr(const int* __restrict__ src,
                                                const int* __restrict__ dst,
                                                const int* __restrict__ rp,
                                                int* __restrict__ fill,
                                                int* __restrict__ col, int E) {
    int i = blockIdx.x * blockDim.x + threadIdx.x;
    if (i < E) {
        int d = dst[i];
        int p = atomicAdd(&fill[d], 1);
        col[rp[d] + p] = src[i];
    }
}

// ---- GEMM: y[r][c] = bf16( dinv[r] * (A[r] @ W)[c] ), A fp32 NxK=64 ----
__global__ __launch_bounds__(256) void gemm64_bf16(const float* __restrict__ A,
                                                   const float* __restrict__ W,
                                                   const float* __restrict__ dinv,
                                                   unsigned short* __restrict__ out,
                                                   int N) {
    __shared__ float sW[64][64];
    __shared__ float sX[64][65];
    int t = threadIdx.x;
    for (int i = t; i < 4096; i += 256) sW[i >> 6][i & 63] = W[i];
    int row0 = blockIdx.x * 64;
    for (int i = t; i < 4096; i += 256) {
        int r = i >> 6, c = i & 63;
        int gr = row0 + r;
        sX[r][c] = (gr < N) ? A[(size_t)gr * 64 + c] : 0.f;
    }
    __syncthreads();
    int r = t >> 2;
    int c0 = (t & 3) * 16;
    float acc[16];
#pragma unroll
    for (int j = 0; j < 16; ++j) acc[j] = 0.f;
#pragma unroll
    for (int k = 0; k < 64; ++k) {
        float xv = sX[r][k];
#pragma unroll
        for (int j = 0; j < 16; ++j) acc[j] += xv * sW[k][c0 + j];
    }
    int gr = row0 + r;
    if (gr < N) {
        float dv = dinv[gr];
        unsigned int pk[8];
#pragma unroll
        for (int j = 0; j < 8; ++j) {
            unsigned int lo = f2bf(acc[2 * j] * dv);
            unsigned int hi = f2bf(acc[2 * j + 1] * dv);
            pk[j] = lo | (hi << 16);
        }
        unsigned int* op = (unsigned int*)(&out[(size_t)gr * 64 + c0]);
        *(uint4*)op = make_uint4(pk[0], pk[1], pk[2], pk[3]);
        *(uint4*)(op + 4) = make_uint4(pk[4], pk[5], pk[6], pk[7]);
    }
}

// ---- fused: agg layer1 (gather y1 bf16) -> relu -> h @ W2 -> y2 bf16 ----
__global__ __launch_bounds__(256) void agg_gemm_kernel(const unsigned short* __restrict__ y1,
                                                       const int* __restrict__ rp,
                                                       const int* __restrict__ col,
                                                       const float* __restrict__ dinv,
                                                       const float* __restrict__ bias,
                                                       const float* __restrict__ W2,
                                                       unsigned short* __restrict__ y2,
                                                       int N) {
    __shared__ float sW2[64][64];
    int t = threadIdx.x;
    for (int i = t; i < 4096; i += 256) sW2[i >> 6][i & 63] = W2[i];
    __syncthreads();

    int wid = blockIdx.x * 4 + (t >> 6);
    int lane = t & 63;
    if (wid >= N) return;
    float di = dinv[wid];
    float accA = bf2f(y1[(size_t)wid * 64 + lane]);
    float accB = 0.f, accC = 0.f, accD = 0.f;
    int e0 = rp[wid], e1 = rp[wid + 1];
    int e = e0;
    for (; e + 4 <= e1; e += 4) {
        int s0 = col[e], s1 = col[e + 1], s2 = col[e + 2], s3 = col[e + 3];
        accA += bf2f(y1[(size_t)s0 * 64 + lane]);
        accB += bf2f(y1[(size_t)s1 * 64 + lane]);
        accC += bf2f(y1[(size_t)s2 * 64 + lane]);
        accD += bf2f(y1[(size_t)s3 * 64 + lane]);
    }
    for (; e < e1; ++e) accA += bf2f(y1[(size_t)col[e] * 64 + lane]);
    float h = (accA + accB) + (accC + accD);
    h = h * di + bias[lane];
    h = h > 0.f ? h : 0.f;

    // y2 = bf16( di * (h @ W2) )
    float p0 = 0.f, p1 = 0.f;
#pragma unroll
    for (int k = 0; k < 64; k += 2) {
        p0 += __shfl(h, k) * sW2[k][lane];
        p1 += __shfl(h, k + 1) * sW2[k + 1][lane];
    }
    y2[(size_t)wid * 64 + lane] = f2bf((p0 + p1) * di);
}

// ---- agg layer2 (gather y2 bf16) -> relu -> dot Wfc[:64] -> nv scalar ----
__global__ __launch_bounds__(256) void agg_nv_kernel(const unsigned short* __restrict__ y2,
                                                     const int* __restrict__ rp,
                                                     const int* __restrict__ col,
                                                     const float* __restrict__ dinv,
                                                     const float* __restrict__ bias,
                                                     const float* __restrict__ wfc,
                                                     float* __restrict__ nv, int N) {
    int wid = blockIdx.x * 4 + (threadIdx.x >> 6);
    int lane = threadIdx.x & 63;
    if (wid >= N) return;
    float di = dinv[wid];
    float accA = bf2f(y2[(size_t)wid * 64 + lane]);
    float accB = 0.f, accC = 0.f, accD = 0.f;
    int e0 = rp[wid], e1 = rp[wid + 1];
    int e = e0;
    for (; e + 4 <= e1; e += 4) {
        int s0 = col[e], s1 = col[e + 1], s2 = col[e + 2], s3 = col[e + 3];
        accA += bf2f(y2[(size_t)s0 * 64 + lane]);
        accB += bf2f(y2[(size_t)s1 * 64 + lane]);
        accC += bf2f(y2[(size_t)s2 * 64 + lane]);
        accD += bf2f(y2[(size_t)s3 * 64 + lane]);
    }
    for (; e < e1; ++e) accA += bf2f(y2[(size_t)col[e] * 64 + lane]);
    float h = (accA + accB) + (accC + accD);
    h = h * di + bias[lane];
    h = h > 0.f ? h : 0.f;
    float p = h * wfc[lane];
#pragma unroll
    for (int off = 32; off; off >>= 1) p += __shfl_down(p, off);
    if (lane == 0) nv[wid] = p;
}

// ---- fused edge-pred + route sum (wave per route) ----
__global__ __launch_bounds__(256) void route_kernel(const float* __restrict__ nv,
                                                    const int* __restrict__ src,
                                                    const float* __restrict__ ea,
                                                    const float* __restrict__ wfc,
                                                    const float* __restrict__ bfc,
                                                    const int* __restrict__ routes,
                                                    float* __restrict__ out, int R) {
    int r = blockIdx.x * 4 + (threadIdx.x >> 6);
    int lane = threadIdx.x & 63;
    if (r >= R) return;
    int s0 = routes[2 * r], s1 = routes[2 * r + 1];
    float w0 = wfc[64], w1 = wfc[65], b = bfc[0];
    float acc = 0.f;
    for (int e = s0 + lane; e < s1; e += 64) {
        float2 a = *(const float2*)(&ea[2 * (size_t)e]);
        acc += nv[src[e]] + a.x * w0 + a.y * w1 + b;
    }
#pragma unroll
    for (int off = 32; off; off >>= 1) acc += __shfl_down(acc, off);
    if (lane == 0) out[r] = acc;
}

extern "C" void kernel_launch(void* const* d_in, const int* in_sizes, int n_in,
                              void* d_out, int out_size, void* d_ws, size_t ws_size,
                              hipStream_t stream) {
    const float* x   = (const float*)d_in[0];
    const float* ea  = (const float*)d_in[1];
    const float* W1  = (const float*)d_in[2];
    const float* b1  = (const float*)d_in[3];
    const float* W2  = (const float*)d_in[4];
    const float* b2  = (const float*)d_in[5];
    const float* Wfc = (const float*)d_in[6];
    const float* bfc = (const float*)d_in[7];
    const int* eidx  = (const int*)d_in[8];
    const int* routes= (const int*)d_in[9];

    int N = in_sizes[0] / 64;
    int E = in_sizes[8] / 2;
    int R = in_sizes[9] / 2;
    const int* src = eidx;
    const int* dst = eidx + E;

    char* ws = (char*)d_ws;
    size_t off = 0;
    auto alloc = [&](size_t bytes) -> void* {
        off = (off + 255) & ~(size_t)255;
        void* p = ws + off;
        off += bytes;
        return p;
    };

    float* dinv = (float*)alloc((size_t)N * 4);
    int*   deg  = (int*)alloc((size_t)N * 4);
    int*   rp   = (int*)alloc((size_t)(N + 1) * 4);
    int*   fill = (int*)alloc((size_t)N * 4);
    int*   col  = (int*)alloc((size_t)E * 4);
    unsigned short* y1 = (unsigned short*)alloc((size_t)N * 64 * 2);
    unsigned short* y2 = (unsigned short*)alloc((size_t)N * 64 * 2);
    float* nv   = (float*)alloc((size_t)N * 4);
    int*   bsum = (int*)alloc(4096);

    hipMemsetAsync(deg, 0, (size_t)N * 4, stream);
    hipMemsetAsync(fill, 0, (size_t)N * 4, stream);

    int eb = (E + 255) / 256;
    int nb = (N + 255) / 256;
    int nb1024 = (N + SCAN_BLK - 1) / SCAN_BLK;

    count_deg<<<eb, 256, 0, stream>>>(dst, deg, E);
    scan1<<<nb1024, 256, 0, stream>>>(deg, rp, dinv, bsum, N);
    scan2<<<1, 1024, 0, stream>>>(bsum, nb1024);
    scan3<<<nb, 256, 0, stream>>>(rp, bsum, N, E);
    fill_csr<<<eb, 256, 0, stream>>>(src, dst, rp, fill, col, E);

    // layer 1 GEMM (dinv-prescaled bf16 table)
    gemm64_bf16<<<(N + 63) / 64, 256, 0, stream>>>(x, W1, dinv, y1, N);
    // layer-1 agg + fused layer-2 GEMM -> y2 table
    agg_gemm_kernel<<<(N + 3) / 4, 256, 0, stream>>>(y1, rp, col, dinv, b1, W2, y2, N);
    // layer-2 agg + fused Wfc[:64] dot -> nv
    agg_nv_kernel<<<(N + 3) / 4, 256, 0, stream>>>(y2, rp, col, dinv, b2, Wfc, nv, N);

    route_kernel<<<(R + 3) / 4, 256, 0, stream>>>(nv, src, ea, Wfc, bfc, routes, (float*)d_out, R);
}